// Round 4
// baseline (711.911 us; speedup 1.0000x reference)
//
#include <hip/hip_runtime.h>
#include <hip/hip_bf16.h>
#include <math.h>

#define BATCH   2
#define SEQ     2048
#define D_IN    2048
#define NHEAD   16
#define QK_ROPE 64
#define QK_NOPE 64
#define QK_HEAD 128
#define V_HEAD  128
#define KV_RANK 512
#define D_KVA_P 640          // padded 576 -> 640
#define D_KVB   3072
#define NTOK    (BATCH*SEQ)  // 4096
#define EPS_F   1e-6f

typedef unsigned short u16;
typedef short bf16x8 __attribute__((ext_vector_type(8)));
typedef float f32x4  __attribute__((ext_vector_type(4)));

__device__ __forceinline__ u16 f2bf(float f) {
    unsigned u = __float_as_uint(f);
    return (u16)((u + 0x7fffu + ((u >> 16) & 1u)) >> 16);
}
__device__ __forceinline__ float bf2f(u16 u) {
    return __uint_as_float(((unsigned)u) << 16);
}
__device__ __forceinline__ void gload16(const void* g, void* l) {
    __builtin_amdgcn_global_load_lds((const __attribute__((address_space(1))) unsigned int*)g,
                                     (__attribute__((address_space(3))) unsigned int*)l, 16, 0, 0);
}

// ---------------- fp32 -> bf16 flat convert (4 elems/thread) ----------------
__global__ __launch_bounds__(256) void convert_bf16(const float* __restrict__ src,
                                                    u16* __restrict__ dst, int n4) {
    int gid = blockIdx.x * 256 + threadIdx.x;
    if (gid >= n4) return;
    float4 v = ((const float4*)src)[gid];
    unsigned lo = (unsigned)f2bf(v.x) | ((unsigned)f2bf(v.y) << 16);
    unsigned hi = (unsigned)f2bf(v.z) | ((unsigned)f2bf(v.w) << 16);
    ((uint2*)dst)[gid] = make_uint2(lo, hi);
}

// -------- transpose+convert: src fp32 [K][N] -> dst bf16 [Npad][K] ----------
__global__ __launch_bounds__(256) void transpose_bf16(const float* __restrict__ src,
                                                      u16* __restrict__ dst,
                                                      int N, int K) {
    __shared__ float tile[32][33];
    const int nb = blockIdx.x * 32, kb = blockIdx.y * 32;
    const int tx = threadIdx.x, ty = threadIdx.y;  // 32 x 8
#pragma unroll
    for (int i = 0; i < 4; ++i) {
        int k = kb + ty + 8 * i, n = nb + tx;
        tile[ty + 8 * i][tx] = (n < N) ? src[(size_t)k * N + n] : 0.f;
    }
    __syncthreads();
#pragma unroll
    for (int i = 0; i < 4; ++i) {
        int n = nb + ty + 8 * i, k = kb + tx;
        dst[(size_t)n * K + k] = f2bf(tile[tx][ty + 8 * i]);
    }
}

// ---------------- RoPE cos/sin table -----------------------------------------
__global__ __launch_bounds__(256) void rope_table_kernel(float* __restrict__ tab) {
    int gid = blockIdx.x * 256 + threadIdx.x;  // < SEQ*32
    int i = gid & 31, s = gid >> 5;
    float freq = __expf(-(float)(2 * i) / 64.0f * 9.210340371976184f);
    float ang = (float)s * freq;
    tab[2 * gid]     = cosf(ang);
    tab[2 * gid + 1] = sinf(ang);
}

// ---------------- m97-style bf16 GEMM: C = (A[M,K] @ BT[N,K]^T) * oscale -----
template <bool OBF>
__global__ __launch_bounds__(256) void gemm_bf16(const u16* __restrict__ A,
                                                 const u16* __restrict__ BT,
                                                 float* __restrict__ C,
                                                 u16* __restrict__ Cbf,
                                                 int M, int N, int K, float oscale) {
    __shared__ u16 As[128 * 32];
    __shared__ u16 Bs[128 * 32];
    const int tid = threadIdx.x;
    const int w = tid >> 6, l = tid & 63;
    const int lr = l & 15, lg = l >> 4;
    const int wr = w >> 1, wc = w & 1;
    const int row0 = blockIdx.y * 128, col0 = blockIdx.x * 128;

    f32x4 acc[4][4];
#pragma unroll
    for (int a = 0; a < 4; ++a)
#pragma unroll
        for (int b = 0; b < 4; ++b) acc[a][b] = (f32x4){0.f, 0.f, 0.f, 0.f};

    const u16* ga = A + (size_t)(row0 + 32 * w + (l >> 2)) * K + 8 * (l & 3);
    const u16* gb = BT + (size_t)(col0 + 32 * w + (l >> 2)) * K + 8 * (l & 3);
    u16* la = As + w * 1024;
    u16* lb = Bs + w * 1024;

    for (int k0 = 0; k0 < K; k0 += 32) {
        __syncthreads();
        gload16(ga + k0, la);
        gload16(ga + (size_t)16 * K + k0, la + 512);
        gload16(gb + k0, lb);
        gload16(gb + (size_t)16 * K + k0, lb + 512);
        __syncthreads();
        bf16x8 af[4], bfr[4];
#pragma unroll
        for (int mi = 0; mi < 4; ++mi)
            af[mi] = *(const bf16x8*)&As[(64 * wr + 16 * mi + lr) * 32 + 8 * lg];
#pragma unroll
        for (int ni = 0; ni < 4; ++ni)
            bfr[ni] = *(const bf16x8*)&Bs[(64 * wc + 16 * ni + lr) * 32 + 8 * lg];
#pragma unroll
        for (int mi = 0; mi < 4; ++mi)
#pragma unroll
            for (int ni = 0; ni < 4; ++ni)
                acc[mi][ni] = __builtin_amdgcn_mfma_f32_16x16x32_bf16(af[mi], bfr[ni], acc[mi][ni], 0, 0, 0);
    }
#pragma unroll
    for (int mi = 0; mi < 4; ++mi)
#pragma unroll
        for (int ni = 0; ni < 4; ++ni)
#pragma unroll
            for (int j = 0; j < 4; ++j) {
                int r = row0 + 64 * wr + 16 * mi + 4 * lg + j;
                int c = col0 + 64 * wc + 16 * ni + lr;
                if (OBF) Cbf[(size_t)r * N + c] = f2bf(acc[mi][ni][j] * oscale);
                else     C[(size_t)r * N + c] = acc[mi][ni][j] * oscale;
            }
}

// ---------------- RMS norm: kv fp32 [NTOK][640] cols 0..511 -> bf16 ---------
__global__ __launch_bounds__(256) void rmsnorm_bf(const float* __restrict__ kv,
                                                  const float* __restrict__ w,
                                                  u16* __restrict__ c_norm) {
    __shared__ float red[256];
    const int row = blockIdx.x, t = threadIdx.x;
    const float* src = kv + (size_t)row * D_KVA_P;
    float v0 = src[t], v1 = src[t + 256];
    red[t] = v0 * v0 + v1 * v1;
    __syncthreads();
    for (int s = 128; s > 0; s >>= 1) {
        if (t < s) red[t] += red[t + s];
        __syncthreads();
    }
    const float inv = rsqrtf(red[0] / (float)KV_RANK + EPS_F);
    u16* dst = c_norm + (size_t)row * KV_RANK;
    dst[t]       = f2bf(v0 * inv * w[t]);
    dst[t + 256] = f2bf(v1 * inv * w[t + 256]);
}

// ---------------- RoPE on q_bf in place -------------------------------------
__global__ __launch_bounds__(256) void rope_q_kernel(u16* __restrict__ q_bf,
                                                     const float* __restrict__ tab) {
    const int gid = blockIdx.x * 256 + threadIdx.x;  // < NTOK*16*32
    const int i = gid & 31;
    const int h = (gid >> 5) & (NHEAD - 1);
    const int row = gid >> 9;
    const int s = row & (SEQ - 1);
    const float c = tab[(s * 32 + i) * 2], sn = tab[(s * 32 + i) * 2 + 1];
    u16* p = q_bf + (size_t)row * 2048 + h * QK_HEAD + QK_NOPE + 2 * i;
    float x1 = bf2f(p[0]), x2 = bf2f(p[1]);
    p[0] = f2bf(x1 * c - x2 * sn);
    p[1] = f2bf(x2 * c + x1 * sn);
}

// ---------------- build K_all bf16 [bh][s][128] -----------------------------
__global__ __launch_bounds__(256) void build_k_kernel(const u16* __restrict__ kvdec_bf,
                                                      const float* __restrict__ kv,
                                                      const float* __restrict__ tab,
                                                      u16* __restrict__ K_all) {
    const int gid = blockIdx.x * 256 + threadIdx.x;  // < 2^21
    const int dq = gid & 31;
    const int s = (gid >> 5) & (SEQ - 1);
    const int bh = gid >> 16;
    const int b = bh >> 4, h = bh & 15;
    const size_t bs_row = (size_t)b * SEQ + s;
    u16* dst = K_all + ((size_t)bh * SEQ + s) * 128 + 4 * dq;
    if (dq < 16) {
        const u16* src = kvdec_bf + bs_row * D_KVB + h * 192 + 4 * dq;
        *(ushort2*)dst = *(const ushort2*)src;
        *(ushort2*)(dst + 2) = *(const ushort2*)(src + 2);
    } else {
        const int j0 = 4 * dq - 64;
        const int i0 = j0 >> 1;
        float4 v = *(const float4*)(kv + bs_row * D_KVA_P + KV_RANK + j0);
        float c0 = tab[(s * 32 + i0) * 2],     s0 = tab[(s * 32 + i0) * 2 + 1];
        float c1 = tab[(s * 32 + i0 + 1) * 2], s1 = tab[(s * 32 + i0 + 1) * 2 + 1];
        dst[0] = f2bf(v.x * c0 - v.y * s0);
        dst[1] = f2bf(v.y * c0 + v.x * s0);
        dst[2] = f2bf(v.z * c1 - v.w * s1);
        dst[3] = f2bf(v.w * c1 + v.z * s1);
    }
}

// ---------------- build Vt bf16 [bh][d=128][s] ------------------------------
__global__ __launch_bounds__(256) void build_vt_kernel(const u16* __restrict__ kvdec_bf,
                                                       u16* __restrict__ Vt) {
    __shared__ u16 tile[64][136];
    const int sb = blockIdx.x * 64;
    const int bh = blockIdx.y;
    const int b = bh >> 4, h = bh & 15;
    const int tid = threadIdx.x;
#pragma unroll
    for (int i = 0; i < 4; ++i) {
        int s_loc = (tid >> 4) + 16 * i;
        int d8 = (tid & 15) * 8;
        bf16x8 v = *(const bf16x8*)(kvdec_bf + ((size_t)b * SEQ + sb + s_loc) * D_KVB + h * 192 + 64 + d8);
        *(bf16x8*)&tile[s_loc][d8] = v;
    }
    __syncthreads();
    const int d = tid >> 1;
    const int so = (tid & 1) * 32;
    union { u16 u[32]; bf16x8 v[4]; } out;
#pragma unroll
    for (int j = 0; j < 32; ++j) out.u[j] = tile[so + j][d];
    u16* dst = Vt + ((size_t)bh * 128 + d) * SEQ + sb + so;
#pragma unroll
    for (int k = 0; k < 4; ++k) *(bf16x8*)(dst + 8 * k) = out.v[k];
}

// ---------------- flash attention, swapped operands (q lane-local) ----------
// S^T = mfma(K, Q): lane (lr,lg) holds S[q=lr][key=k0+16f+4lg+j].
// O^T = mfma(V^T, P^T): lane holds O[q=lr][d=16ft+4lg+j]. Stats all in-lane.
#define QTILE 64
#define KTILE 64

__global__ __launch_bounds__(256) void attn_mfma(const u16* __restrict__ q_bf,
                                                 const u16* __restrict__ K_all,
                                                 const u16* __restrict__ Vt,
                                                 u16* __restrict__ attn_bf) {
    __shared__ u16 Plds[4][16 * KTILE];  // per-wave [16 q][64 k], swizzled
    const int qbase = (gridDim.x - 1 - (int)blockIdx.x) * QTILE;  // long blocks first
    const int h = blockIdx.y, b = blockIdx.z;
    const int tid = threadIdx.x;
    const int w = tid >> 6, l = tid & 63;
    const int lr = l & 15, lg = l >> 4;
    const int bh = b * NHEAD + h;
    const u16* Kb = K_all + (size_t)bh * SEQ * 128;
    const u16* Vb = Vt + (size_t)bh * 128 * SEQ;
    const int qg = qbase + 16 * w + lr;  // this lane's q row
    const int swz = (lr & 7) << 4;

    const u16* qrow = q_bf + (size_t)(b * SEQ + qg) * 2048 + h * QK_HEAD;
    bf16x8 qf[4];
#pragma unroll
    for (int dc = 0; dc < 4; ++dc) qf[dc] = *(const bf16x8*)(qrow + dc * 32 + lg * 8);

    f32x4 oacc[8];
#pragma unroll
    for (int ft = 0; ft < 8; ++ft) oacc[ft] = (f32x4){0.f, 0.f, 0.f, 0.f};
    float m_r = -1e30f, l_r = 0.f;

    char* pw = (char*)Plds[w];
    const int nkt = qbase / KTILE + 1;

    for (int kt = 0; kt < nkt; ++kt) {
        const int k0 = kt * KTILE;

        // ---- S^T = K @ Q^T ----
        f32x4 s[4];
        __builtin_amdgcn_s_setprio(1);
#pragma unroll
        for (int f = 0; f < 4; ++f) {
            s[f] = (f32x4){0.f, 0.f, 0.f, 0.f};
#pragma unroll
            for (int dc = 0; dc < 4; ++dc) {
                bf16x8 kf = *(const bf16x8*)(Kb + (size_t)(k0 + 16 * f + lr) * 128 + 32 * dc + 8 * lg);
                s[f] = __builtin_amdgcn_mfma_f32_16x16x32_bf16(kf, qf[dc], s[f], 0, 0, 0);
            }
        }
        __builtin_amdgcn_s_setprio(0);

        // ---- causal mask (diagonal tile only; block-uniform branch) ----
        if (kt == nkt - 1) {
#pragma unroll
            for (int f = 0; f < 4; ++f)
#pragma unroll
                for (int j = 0; j < 4; ++j)
                    if (k0 + 16 * f + 4 * lg + j > qg) s[f][j] = -1e30f;
        }

        // ---- online softmax, q lane-local: in-lane reduce + 2 shfl ----
        float t0 = fmaxf(fmaxf(s[0][0], s[0][1]), fmaxf(s[0][2], s[0][3]));
        float t1 = fmaxf(fmaxf(s[1][0], s[1][1]), fmaxf(s[1][2], s[1][3]));
        float t2 = fmaxf(fmaxf(s[2][0], s[2][1]), fmaxf(s[2][2], s[2][3]));
        float t3 = fmaxf(fmaxf(s[3][0], s[3][1]), fmaxf(s[3][2], s[3][3]));
        float t = fmaxf(fmaxf(t0, t1), fmaxf(t2, t3));
        t = fmaxf(t, __shfl_xor(t, 16));
        t = fmaxf(t, __shfl_xor(t, 32));
        float newm = fmaxf(m_r, t);
        float sf_ = __expf(m_r - newm);
        m_r = newm;
        float rs = 0.f;
#pragma unroll
        for (int f = 0; f < 4; ++f)
#pragma unroll
            for (int j = 0; j < 4; ++j) {
                float p = __expf(s[f][j] - newm);
                s[f][j] = p;
                rs += p;
            }
        rs += __shfl_xor(rs, 16);
        rs += __shfl_xor(rs, 32);
        l_r = l_r * sf_ + rs;
#pragma unroll
        for (int ft = 0; ft < 8; ++ft)
#pragma unroll
            for (int j = 0; j < 4; ++j) oacc[ft][j] *= sf_;

        // ---- P -> wave-private LDS (8B packed writes, swizzled) ----
#pragma unroll
        for (int f = 0; f < 4; ++f) {
            union { u16 u[4]; uint2 v; } pk;
#pragma unroll
            for (int j = 0; j < 4; ++j) pk.u[j] = f2bf(s[f][j]);
            int byte = lr * 128 + (16 * f + 4 * lg) * 2;
            *(uint2*)(pw + (byte ^ swz)) = pk.v;
        }
        asm volatile("s_waitcnt lgkmcnt(0)" ::: "memory");
        bf16x8 pfr[2];
#pragma unroll
        for (int ks = 0; ks < 2; ++ks) {
            int byte = lr * 128 + 64 * ks + 16 * lg;
            pfr[ks] = *(const bf16x8*)(pw + (byte ^ swz));
        }

        // ---- O^T += V^T @ P^T ----
        __builtin_amdgcn_s_setprio(1);
#pragma unroll
        for (int ft = 0; ft < 8; ++ft) {
            int d = 16 * ft + lr;
#pragma unroll
            for (int ks = 0; ks < 2; ++ks) {
                bf16x8 vf = *(const bf16x8*)(Vb + (size_t)d * SEQ + k0 + 32 * ks + 8 * lg);
                oacc[ft] = __builtin_amdgcn_mfma_f32_16x16x32_bf16(vf, pfr[ks], oacc[ft], 0, 0, 0);
            }
        }
        __builtin_amdgcn_s_setprio(0);
    }

    // ---- epilogue: lane owns q=qg, d = 16ft+4lg+j ----
    const float inv = 1.0f / l_r;
    u16* orow = attn_bf + (size_t)(b * SEQ + qg) * 2048 + h * V_HEAD;
#pragma unroll
    for (int ft = 0; ft < 8; ++ft) {
        union { u16 u[4]; uint2 v; } ok;
#pragma unroll
        for (int j = 0; j < 4; ++j) ok.u[j] = f2bf(oacc[ft][j] * inv);
        *(uint2*)(orow + 16 * ft + 4 * lg) = ok.v;
    }
}

// ------------------------------------------------------------------
extern "C" void kernel_launch(void* const* d_in, const int* in_sizes, int n_in,
                              void* d_out, int out_size, void* d_ws, size_t ws_size,
                              hipStream_t stream) {
    const float* x         = (const float*)d_in[0];
    const float* w_query   = (const float*)d_in[1];
    const float* wkv_a     = (const float*)d_in[2];
    const float* wkv_b     = (const float*)d_in[3];
    const float* kv_norm_w = (const float*)d_in[4];
    const float* out_proj  = (const float*)d_in[5];

    u16* x_bf     = (u16*)d_ws;                       // 8M u16 (aliased by attn_bf)
    u16* q_bf     = x_bf + (size_t)8388608;           // 8M
    u16* c_norm   = q_bf + (size_t)8388608;           // 2M
    u16* kvdec_bf = c_norm + (size_t)2097152;         // 12.58M
    u16* K_all    = kvdec_bf + (size_t)12582912;      // 8.39M
    u16* Vt       = K_all + (size_t)8388608;          // 8.39M
    u16* wqT      = Vt + (size_t)8388608;             // 4M
    u16* wkvaT    = wqT + (size_t)4194304;            // 1.31M
    u16* wkvbT    = wkvaT + (size_t)1310720;          // 1.57M
    u16* opT      = wkvbT + (size_t)1572864;          // 4M
    float* kv     = (float*)(opT + (size_t)4194304);  // 2.62M floats
    float* tab    = kv + (size_t)2621440;             // 131072 floats
    u16* attn_bf  = x_bf;                             // alias (x_bf dead after kv GEMM)
    float* out = (float*)d_out;

    dim3 tb(32, 8);
    const float qscale = 0.08838834764831845f;  // 128^-0.5 folded into q GEMM

    convert_bf16<<<8192, 256, 0, stream>>>(x, x_bf, 2097152);
    transpose_bf16<<<dim3(64, 64), tb, 0, stream>>>(w_query, wqT, 2048, 2048);
    transpose_bf16<<<dim3(20, 64), tb, 0, stream>>>(wkv_a, wkvaT, 576, 2048);
    transpose_bf16<<<dim3(96, 16), tb, 0, stream>>>(wkv_b, wkvbT, 3072, 512);
    transpose_bf16<<<dim3(64, 64), tb, 0, stream>>>(out_proj, opT, 2048, 2048);
    rope_table_kernel<<<256, 256, 0, stream>>>(tab);

    gemm_bf16<true><<<dim3(16, 32), 256, 0, stream>>>(x_bf, wqT, nullptr, q_bf, NTOK, 2048, 2048, qscale);
    gemm_bf16<false><<<dim3(5, 32), 256, 0, stream>>>(x_bf, wkvaT, kv, nullptr, NTOK, D_KVA_P, 2048, 1.0f);
    rmsnorm_bf<<<NTOK, 256, 0, stream>>>(kv, kv_norm_w, c_norm);
    gemm_bf16<true><<<dim3(24, 32), 256, 0, stream>>>(c_norm, wkvbT, nullptr, kvdec_bf, NTOK, D_KVB, KV_RANK, 1.0f);

    rope_q_kernel<<<8192, 256, 0, stream>>>(q_bf, tab);
    build_k_kernel<<<8192, 256, 0, stream>>>(kvdec_bf, kv, tab, K_all);
    build_vt_kernel<<<dim3(32, 32), 256, 0, stream>>>(kvdec_bf, Vt);

    attn_mfma<<<dim3(SEQ / QTILE, NHEAD, BATCH), 256, 0, stream>>>(q_bf, K_all, Vt, attn_bf);

    gemm_bf16<false><<<dim3(16, 32), 256, 0, stream>>>(attn_bf, opT, out, nullptr, NTOK, 2048, 2048, 1.0f);
}

// Round 5
// 331.830 us; speedup vs baseline: 2.1454x; 2.1454x over previous
//
#include <hip/hip_runtime.h>
#include <hip/hip_bf16.h>
#include <math.h>

#define BATCH   2
#define SEQ     2048
#define D_IN    2048
#define NHEAD   16
#define QK_ROPE 64
#define QK_NOPE 64
#define QK_HEAD 128
#define V_HEAD  128
#define KV_RANK 512
#define D_KVA_P 640          // padded 576 -> 640
#define D_KVB   3072
#define NTOK    (BATCH*SEQ)  // 4096
#define EPS_F   1e-6f

typedef unsigned short u16;
typedef short bf16x8 __attribute__((ext_vector_type(8)));
typedef float f32x4  __attribute__((ext_vector_type(4)));

__device__ __forceinline__ u16 f2bf(float f) {
    unsigned u = __float_as_uint(f);
    return (u16)((u + 0x7fffu + ((u >> 16) & 1u)) >> 16);
}
__device__ __forceinline__ float bf2f(u16 u) {
    return __uint_as_float(((unsigned)u) << 16);
}
__device__ __forceinline__ void gload16(const void* g, void* l) {
    __builtin_amdgcn_global_load_lds((const __attribute__((address_space(1))) unsigned int*)g,
                                     (__attribute__((address_space(3))) unsigned int*)l, 16, 0, 0);
}

// ---------------- fp32 -> bf16 flat convert (4 elems/thread) ----------------
__global__ __launch_bounds__(256) void convert_bf16(const float* __restrict__ src,
                                                    u16* __restrict__ dst, int n4) {
    int gid = blockIdx.x * 256 + threadIdx.x;
    if (gid >= n4) return;
    float4 v = ((const float4*)src)[gid];
    unsigned lo = (unsigned)f2bf(v.x) | ((unsigned)f2bf(v.y) << 16);
    unsigned hi = (unsigned)f2bf(v.z) | ((unsigned)f2bf(v.w) << 16);
    ((uint2*)dst)[gid] = make_uint2(lo, hi);
}

// -------- transpose+convert: src fp32 [K][N] -> dst bf16 [Npad][K] ----------
__global__ __launch_bounds__(256) void transpose_bf16(const float* __restrict__ src,
                                                      u16* __restrict__ dst,
                                                      int N, int K) {
    __shared__ float tile[32][33];
    const int nb = blockIdx.x * 32, kb = blockIdx.y * 32;
    const int tx = threadIdx.x, ty = threadIdx.y;  // 32 x 8
#pragma unroll
    for (int i = 0; i < 4; ++i) {
        int k = kb + ty + 8 * i, n = nb + tx;
        tile[ty + 8 * i][tx] = (n < N) ? src[(size_t)k * N + n] : 0.f;
    }
    __syncthreads();
#pragma unroll
    for (int i = 0; i < 4; ++i) {
        int n = nb + ty + 8 * i, k = kb + tx;
        dst[(size_t)n * K + k] = f2bf(tile[tx][ty + 8 * i]);
    }
}

// ---------------- RoPE cos/sin table -----------------------------------------
__global__ __launch_bounds__(256) void rope_table_kernel(float* __restrict__ tab) {
    int gid = blockIdx.x * 256 + threadIdx.x;  // < SEQ*32
    int i = gid & 31, s = gid >> 5;
    float freq = __expf(-(float)(2 * i) / 64.0f * 9.210340371976184f);
    float ang = (float)s * freq;
    tab[2 * gid]     = cosf(ang);
    tab[2 * gid + 1] = sinf(ang);
}

// ---------------- m97-style bf16 GEMM: C = (A[M,K] @ BT[N,K]^T) * oscale -----
template <bool OBF>
__global__ __launch_bounds__(256) void gemm_bf16(const u16* __restrict__ A,
                                                 const u16* __restrict__ BT,
                                                 float* __restrict__ C,
                                                 u16* __restrict__ Cbf,
                                                 int M, int N, int K, float oscale) {
    __shared__ u16 As[128 * 32];
    __shared__ u16 Bs[128 * 32];
    const int tid = threadIdx.x;
    const int w = tid >> 6, l = tid & 63;
    const int lr = l & 15, lg = l >> 4;
    const int wr = w >> 1, wc = w & 1;
    const int row0 = blockIdx.y * 128, col0 = blockIdx.x * 128;

    f32x4 acc[4][4];
#pragma unroll
    for (int a = 0; a < 4; ++a)
#pragma unroll
        for (int b = 0; b < 4; ++b) acc[a][b] = (f32x4){0.f, 0.f, 0.f, 0.f};

    const u16* ga = A + (size_t)(row0 + 32 * w + (l >> 2)) * K + 8 * (l & 3);
    const u16* gb = BT + (size_t)(col0 + 32 * w + (l >> 2)) * K + 8 * (l & 3);
    u16* la = As + w * 1024;
    u16* lb = Bs + w * 1024;

    for (int k0 = 0; k0 < K; k0 += 32) {
        __syncthreads();
        gload16(ga + k0, la);
        gload16(ga + (size_t)16 * K + k0, la + 512);
        gload16(gb + k0, lb);
        gload16(gb + (size_t)16 * K + k0, lb + 512);
        __syncthreads();
        bf16x8 af[4], bfr[4];
#pragma unroll
        for (int mi = 0; mi < 4; ++mi)
            af[mi] = *(const bf16x8*)&As[(64 * wr + 16 * mi + lr) * 32 + 8 * lg];
#pragma unroll
        for (int ni = 0; ni < 4; ++ni)
            bfr[ni] = *(const bf16x8*)&Bs[(64 * wc + 16 * ni + lr) * 32 + 8 * lg];
#pragma unroll
        for (int mi = 0; mi < 4; ++mi)
#pragma unroll
            for (int ni = 0; ni < 4; ++ni)
                acc[mi][ni] = __builtin_amdgcn_mfma_f32_16x16x32_bf16(af[mi], bfr[ni], acc[mi][ni], 0, 0, 0);
    }
#pragma unroll
    for (int mi = 0; mi < 4; ++mi)
#pragma unroll
        for (int ni = 0; ni < 4; ++ni)
#pragma unroll
            for (int j = 0; j < 4; ++j) {
                int r = row0 + 64 * wr + 16 * mi + 4 * lg + j;
                int c = col0 + 64 * wc + 16 * ni + lr;
                if (OBF) Cbf[(size_t)r * N + c] = f2bf(acc[mi][ni][j] * oscale);
                else     C[(size_t)r * N + c] = acc[mi][ni][j] * oscale;
            }
}

// ---------------- RMS norm: kv fp32 [NTOK][640] cols 0..511 -> bf16 ---------
__global__ __launch_bounds__(256) void rmsnorm_bf(const float* __restrict__ kv,
                                                  const float* __restrict__ w,
                                                  u16* __restrict__ c_norm) {
    __shared__ float red[256];
    const int row = blockIdx.x, t = threadIdx.x;
    const float* src = kv + (size_t)row * D_KVA_P;
    float v0 = src[t], v1 = src[t + 256];
    red[t] = v0 * v0 + v1 * v1;
    __syncthreads();
    for (int s = 128; s > 0; s >>= 1) {
        if (t < s) red[t] += red[t + s];
        __syncthreads();
    }
    const float inv = rsqrtf(red[0] / (float)KV_RANK + EPS_F);
    u16* dst = c_norm + (size_t)row * KV_RANK;
    dst[t]       = f2bf(v0 * inv * w[t]);
    dst[t + 256] = f2bf(v1 * inv * w[t + 256]);
}

// ---------------- RoPE on q_bf in place -------------------------------------
__global__ __launch_bounds__(256) void rope_q_kernel(u16* __restrict__ q_bf,
                                                     const float* __restrict__ tab) {
    const int gid = blockIdx.x * 256 + threadIdx.x;  // < NTOK*16*32
    const int i = gid & 31;
    const int h = (gid >> 5) & (NHEAD - 1);
    const int row = gid >> 9;
    const int s = row & (SEQ - 1);
    const float c = tab[(s * 32 + i) * 2], sn = tab[(s * 32 + i) * 2 + 1];
    u16* p = q_bf + (size_t)row * 2048 + h * QK_HEAD + QK_NOPE + 2 * i;
    float x1 = bf2f(p[0]), x2 = bf2f(p[1]);
    p[0] = f2bf(x1 * c - x2 * sn);
    p[1] = f2bf(x2 * c + x1 * sn);
}

// ---------------- build K_all bf16 [bh][s][128], 16B-chunk XOR-swizzled -----
// chunk byte offset within 256B row is XORed with ((s&7)<<4); consumer
// (attn LDS staging copies rows verbatim) reads with the same XOR.
__global__ __launch_bounds__(256) void build_k_kernel(const u16* __restrict__ kvdec_bf,
                                                      const float* __restrict__ kv,
                                                      const float* __restrict__ tab,
                                                      u16* __restrict__ K_all) {
    const int gid = blockIdx.x * 256 + threadIdx.x;  // < 2^21
    const int dq = gid & 31;
    const int s = (gid >> 5) & (SEQ - 1);
    const int bh = gid >> 16;
    const int b = bh >> 4, h = bh & 15;
    const size_t bs_row = (size_t)b * SEQ + s;
    const int boff = (8 * dq) ^ ((s & 7) << 4);      // swizzled byte offset in row
    u16* dst = K_all + ((size_t)bh * SEQ + s) * 128 + (boff >> 1);
    if (dq < 16) {
        const u16* src = kvdec_bf + bs_row * D_KVB + h * 192 + 4 * dq;
        *(ushort2*)dst = *(const ushort2*)src;
        *(ushort2*)(dst + 2) = *(const ushort2*)(src + 2);
    } else {
        const int j0 = 4 * dq - 64;
        const int i0 = j0 >> 1;
        float4 v = *(const float4*)(kv + bs_row * D_KVA_P + KV_RANK + j0);
        float c0 = tab[(s * 32 + i0) * 2],     s0 = tab[(s * 32 + i0) * 2 + 1];
        float c1 = tab[(s * 32 + i0 + 1) * 2], s1 = tab[(s * 32 + i0 + 1) * 2 + 1];
        dst[0] = f2bf(v.x * c0 - v.y * s0);
        dst[1] = f2bf(v.y * c0 + v.x * s0);
        dst[2] = f2bf(v.z * c1 - v.w * s1);
        dst[3] = f2bf(v.w * c1 + v.z * s1);
    }
}

// ---------------- build Vt bf16 [bh][d=128][s], swizzled per 128B block -----
// within each 64-key (128B) block, byte offset XORed with ((d&7)<<4).
__global__ __launch_bounds__(256) void build_vt_kernel(const u16* __restrict__ kvdec_bf,
                                                       u16* __restrict__ Vt) {
    __shared__ u16 tile[64][136];
    const int sb = blockIdx.x * 64;
    const int bh = blockIdx.y;
    const int b = bh >> 4, h = bh & 15;
    const int tid = threadIdx.x;
#pragma unroll
    for (int i = 0; i < 4; ++i) {
        int s_loc = (tid >> 4) + 16 * i;
        int d8 = (tid & 15) * 8;
        bf16x8 v = *(const bf16x8*)(kvdec_bf + ((size_t)b * SEQ + sb + s_loc) * D_KVB + h * 192 + 64 + d8);
        *(bf16x8*)&tile[s_loc][d8] = v;
    }
    __syncthreads();
    const int d = tid >> 1;
    const int so = (tid & 1) * 32;
    union { u16 u[32]; bf16x8 v[4]; } out;
#pragma unroll
    for (int j = 0; j < 32; ++j) out.u[j] = tile[so + j][d];
    u16* rowp = Vt + ((size_t)bh * 128 + d) * SEQ;
#pragma unroll
    for (int k = 0; k < 4; ++k) {
        int g = sb + so + 8 * k;
        *(bf16x8*)(rowp + (g & ~63) + ((g & 63) ^ ((d & 7) << 3))) = out.v[k];
    }
}

// ---------------- flash attention: staged LDS double-buffer -----------------
// 512 thr (8 waves), QTILE=128 (16 q-rows/wave), KTILE=64.
// S^T = mfma(K,Q), O^T = mfma(V^T,P^T): q is lane-local, stats in-lane.
// K/V tiles staged via global_load_lds (pre-swizzled global layout);
// 2-phase prefetch with counted vmcnt(4); 2 raw barriers per tile.
#define QTILE 128
#define KTILE 64

__global__ __launch_bounds__(512, 4) void attn_mfma(const u16* __restrict__ q_bf,
                                                    const u16* __restrict__ K_all,
                                                    const u16* __restrict__ Vt,
                                                    u16* __restrict__ attn_bf) {
    __shared__ u16 Kbuf[2][KTILE * 128];   // 2 x 16KB
    __shared__ u16 Vbuf[2][128 * KTILE];   // 2 x 16KB
    __shared__ u16 Plds[8][16 * KTILE];    // 16KB, wave-private

    // XCD-aware flat mapping: idx%8 == bh%8 -> one XCD owns 4 heads entirely
    const int idx = blockIdx.x;                       // 0..511
    const int bh = (idx & 7) + 8 * (idx >> 7);
    const int qb = (idx >> 3) & 15;
    const int qbase = (15 - qb) * QTILE;              // long blocks first
    const int b = bh >> 4, h = bh & 15;

    const int tid = threadIdx.x;
    const int w = tid >> 6, l = tid & 63;
    const int lr = l & 15, lg = l >> 4;
    const u16* Kb = K_all + (size_t)bh * SEQ * 128;
    const u16* Vb = Vt + (size_t)bh * 128 * SEQ;
    const int qg = qbase + 16 * w + lr;
    const int sw = (lr & 7) << 3;                     // u16-index XOR

    const u16* qrow = q_bf + (size_t)(b * SEQ + qg) * 2048 + h * QK_HEAD;
    bf16x8 qf[4];
#pragma unroll
    for (int dc = 0; dc < 4; ++dc) qf[dc] = *(const bf16x8*)(qrow + dc * 32 + lg * 8);

    f32x4 oacc[8];
#pragma unroll
    for (int ft = 0; ft < 8; ++ft) oacc[ft] = (f32x4){0.f, 0.f, 0.f, 0.f};
    float m_r = -1e30f, l_r = 0.f;

    u16* pw = Plds[w];
    const int nkt = qbase / KTILE + 2;

    auto stage = [&](int bufi, int kt) {
        const int k0 = kt * KTILE;
        u16* kb = Kbuf[bufi];
        u16* vb = Vbuf[bufi];
#pragma unroll
        for (int it = 0; it < 2; ++it) {              // K: 1024 chunks / 512 thr
            int ci = it * 512 + tid;
            gload16(Kb + (((size_t)(k0 + (ci >> 4))) << 7) + ((ci & 15) << 3),
                    kb + ((it * 512 + (w << 6)) << 3));
        }
#pragma unroll
        for (int it = 0; it < 2; ++it) {              // V: 1024 chunks
            int ci = it * 512 + tid;
            gload16(Vb + (size_t)(ci >> 3) * SEQ + k0 + ((ci & 7) << 3),
                    vb + ((it * 512 + (w << 6)) << 3));
        }
    };

    stage(0, 0);
    int cur = 0;
    for (int kt = 0; kt < nkt; ++kt) {
        const int k0 = kt * KTILE;
        if (kt + 1 < nkt) {
            stage(cur ^ 1, kt + 1);
            asm volatile("s_waitcnt vmcnt(4)" ::: "memory");
        } else {
            asm volatile("s_waitcnt vmcnt(0)" ::: "memory");
        }
        __builtin_amdgcn_s_barrier();
        __builtin_amdgcn_sched_barrier(0);

        if (k0 <= qbase + 16 * w + 15) {              // wave-uniform skip
            const u16* kb = Kbuf[cur];
            const u16* vb = Vbuf[cur];

            // ---- S^T = K @ Q^T ----
            f32x4 s[4];
            __builtin_amdgcn_s_setprio(1);
#pragma unroll
            for (int f = 0; f < 4; ++f) {
                s[f] = (f32x4){0.f, 0.f, 0.f, 0.f};
#pragma unroll
                for (int dc = 0; dc < 4; ++dc) {
                    bf16x8 kf = *(const bf16x8*)&kb[(16 * f + lr) * 128 + ((32 * dc + 8 * lg) ^ sw)];
                    s[f] = __builtin_amdgcn_mfma_f32_16x16x32_bf16(kf, qf[dc], s[f], 0, 0, 0);
                }
            }
            __builtin_amdgcn_s_setprio(0);

            // ---- causal mask (diagonal region only) ----
            if (k0 + KTILE - 1 > qbase + 16 * w) {
#pragma unroll
                for (int f = 0; f < 4; ++f)
#pragma unroll
                    for (int j = 0; j < 4; ++j)
                        if (k0 + 16 * f + 4 * lg + j > qg) s[f][j] = -1e30f;
            }

            // ---- online softmax, all in-lane + 2 shfl ----
            float t0 = fmaxf(fmaxf(s[0][0], s[0][1]), fmaxf(s[0][2], s[0][3]));
            float t1 = fmaxf(fmaxf(s[1][0], s[1][1]), fmaxf(s[1][2], s[1][3]));
            float t2 = fmaxf(fmaxf(s[2][0], s[2][1]), fmaxf(s[2][2], s[2][3]));
            float t3 = fmaxf(fmaxf(s[3][0], s[3][1]), fmaxf(s[3][2], s[3][3]));
            float t = fmaxf(fmaxf(t0, t1), fmaxf(t2, t3));
            t = fmaxf(t, __shfl_xor(t, 16));
            t = fmaxf(t, __shfl_xor(t, 32));
            float newm = fmaxf(m_r, t);
            float sf_ = __expf(m_r - newm);
            m_r = newm;
            float rs = 0.f;
#pragma unroll
            for (int f = 0; f < 4; ++f)
#pragma unroll
                for (int j = 0; j < 4; ++j) {
                    float p = __expf(s[f][j] - newm);
                    s[f][j] = p;
                    rs += p;
                }
            rs += __shfl_xor(rs, 16);
            rs += __shfl_xor(rs, 32);
            l_r = l_r * sf_ + rs;
#pragma unroll
            for (int ft = 0; ft < 8; ++ft)
#pragma unroll
                for (int j = 0; j < 4; ++j) oacc[ft][j] *= sf_;

            // ---- P -> wave-private LDS, re-layout to B-fragment ----
#pragma unroll
            for (int f = 0; f < 4; ++f) {
                union { u16 u[4]; uint2 v; } pk;
#pragma unroll
                for (int j = 0; j < 4; ++j) pk.u[j] = f2bf(s[f][j]);
                *(uint2*)&pw[lr * 64 + ((16 * f + 4 * lg) ^ sw)] = pk.v;
            }
            asm volatile("s_waitcnt lgkmcnt(0)" ::: "memory");
            bf16x8 pfr[2];
#pragma unroll
            for (int ks = 0; ks < 2; ++ks)
                pfr[ks] = *(const bf16x8*)&pw[lr * 64 + ((32 * ks + 8 * lg) ^ sw)];

            // ---- O^T += V^T @ P^T ----
            __builtin_amdgcn_s_setprio(1);
#pragma unroll
            for (int ft = 0; ft < 8; ++ft) {
                int d = 16 * ft + lr;
#pragma unroll
                for (int ks = 0; ks < 2; ++ks) {
                    bf16x8 vf = *(const bf16x8*)&vb[d * 64 + ((32 * ks + 8 * lg) ^ sw)];
                    oacc[ft] = __builtin_amdgcn_mfma_f32_16x16x32_bf16(vf, pfr[ks], oacc[ft], 0, 0, 0);
                }
            }
            __builtin_amdgcn_s_setprio(0);
        }
        __builtin_amdgcn_s_barrier();
        cur ^= 1;
    }

    // ---- epilogue: lane owns q=qg, d = 16ft+4lg+j ----
    const float inv = 1.0f / l_r;
    u16* orow = attn_bf + (size_t)(b * SEQ + qg) * 2048 + h * V_HEAD;
#pragma unroll
    for (int ft = 0; ft < 8; ++ft) {
        union { u16 u[4]; uint2 v; } ok;
#pragma unroll
        for (int j = 0; j < 4; ++j) ok.u[j] = f2bf(oacc[ft][j] * inv);
        *(uint2*)(orow + 16 * ft + 4 * lg) = ok.v;
    }
}

// ------------------------------------------------------------------
extern "C" void kernel_launch(void* const* d_in, const int* in_sizes, int n_in,
                              void* d_out, int out_size, void* d_ws, size_t ws_size,
                              hipStream_t stream) {
    const float* x         = (const float*)d_in[0];
    const float* w_query   = (const float*)d_in[1];
    const float* wkv_a     = (const float*)d_in[2];
    const float* wkv_b     = (const float*)d_in[3];
    const float* kv_norm_w = (const float*)d_in[4];
    const float* out_proj  = (const float*)d_in[5];

    u16* x_bf     = (u16*)d_ws;                       // 8M u16 (aliased by attn_bf)
    u16* q_bf     = x_bf + (size_t)8388608;           // 8M
    u16* c_norm   = q_bf + (size_t)8388608;           // 2M
    u16* kvdec_bf = c_norm + (size_t)2097152;         // 12.58M
    u16* K_all    = kvdec_bf + (size_t)12582912;      // 8.39M
    u16* Vt       = K_all + (size_t)8388608;          // 8.39M
    u16* wqT      = Vt + (size_t)8388608;             // 4M
    u16* wkvaT    = wqT + (size_t)4194304;            // 1.31M
    u16* wkvbT    = wkvaT + (size_t)1310720;          // 1.57M
    u16* opT      = wkvbT + (size_t)1572864;          // 4M
    float* kv     = (float*)(opT + (size_t)4194304);  // 2.62M floats
    float* tab    = kv + (size_t)2621440;             // 131072 floats
    u16* attn_bf  = x_bf;                             // alias (x_bf dead after kv GEMM)
    float* out = (float*)d_out;

    dim3 tb(32, 8);
    const float qscale = 0.08838834764831845f;  // 128^-0.5 folded into q GEMM

    convert_bf16<<<8192, 256, 0, stream>>>(x, x_bf, 2097152);
    transpose_bf16<<<dim3(64, 64), tb, 0, stream>>>(w_query, wqT, 2048, 2048);
    transpose_bf16<<<dim3(20, 64), tb, 0, stream>>>(wkv_a, wkvaT, 576, 2048);
    transpose_bf16<<<dim3(96, 16), tb, 0, stream>>>(wkv_b, wkvbT, 3072, 512);
    transpose_bf16<<<dim3(64, 64), tb, 0, stream>>>(out_proj, opT, 2048, 2048);
    rope_table_kernel<<<256, 256, 0, stream>>>(tab);

    gemm_bf16<true><<<dim3(16, 32), 256, 0, stream>>>(x_bf, wqT, nullptr, q_bf, NTOK, 2048, 2048, qscale);
    gemm_bf16<false><<<dim3(5, 32), 256, 0, stream>>>(x_bf, wkvaT, kv, nullptr, NTOK, D_KVA_P, 2048, 1.0f);
    rmsnorm_bf<<<NTOK, 256, 0, stream>>>(kv, kv_norm_w, c_norm);
    gemm_bf16<true><<<dim3(24, 32), 256, 0, stream>>>(c_norm, wkvbT, nullptr, kvdec_bf, NTOK, D_KVB, KV_RANK, 1.0f);

    rope_q_kernel<<<8192, 256, 0, stream>>>(q_bf, tab);
    build_k_kernel<<<8192, 256, 0, stream>>>(kvdec_bf, kv, tab, K_all);
    build_vt_kernel<<<dim3(32, 32), 256, 0, stream>>>(kvdec_bf, Vt);

    attn_mfma<<<512, 512, 0, stream>>>(q_bf, K_all, Vt, attn_bf);

    gemm_bf16<false><<<dim3(16, 32), 256, 0, stream>>>(attn_bf, opT, out, nullptr, NTOK, 2048, 2048, 1.0f);
}

// Round 6
// 305.438 us; speedup vs baseline: 2.3308x; 1.0864x over previous
//
#include <hip/hip_runtime.h>
#include <hip/hip_bf16.h>
#include <math.h>

#define BATCH   2
#define SEQ     2048
#define D_IN    2048
#define NHEAD   16
#define QK_ROPE 64
#define QK_NOPE 64
#define QK_HEAD 128
#define V_HEAD  128
#define KV_RANK 512
#define KV_W    640          // kv row stride (576 padded to 640)
#define NTOK    (BATCH*SEQ)  // 4096
#define EPS_F   1e-6f

typedef unsigned short u16;
typedef short bf16x8 __attribute__((ext_vector_type(8)));
typedef float f32x4  __attribute__((ext_vector_type(4)));

__device__ __forceinline__ u16 f2bf(float f) {
    unsigned u = __float_as_uint(f);
    return (u16)((u + 0x7fffu + ((u >> 16) & 1u)) >> 16);
}
__device__ __forceinline__ float bf2f(u16 u) {
    return __uint_as_float(((unsigned)u) << 16);
}
__device__ __forceinline__ void gload16(const void* g, void* l) {
    __builtin_amdgcn_global_load_lds((const __attribute__((address_space(1))) unsigned int*)g,
                                     (__attribute__((address_space(3))) unsigned int*)l, 16, 0, 0);
}

// ---------------- fp32 -> bf16 flat convert (4 elems/thread) ----------------
__global__ __launch_bounds__(256) void convert_bf16(const float* __restrict__ src,
                                                    u16* __restrict__ dst, int n4) {
    int gid = blockIdx.x * 256 + threadIdx.x;
    if (gid >= n4) return;
    float4 v = ((const float4*)src)[gid];
    unsigned lo = (unsigned)f2bf(v.x) | ((unsigned)f2bf(v.y) << 16);
    unsigned hi = (unsigned)f2bf(v.z) | ((unsigned)f2bf(v.w) << 16);
    ((uint2*)dst)[gid] = make_uint2(lo, hi);
}

// -------- transpose+convert: src fp32 [K][N] -> dst bf16 [Npad][K] ----------
__global__ __launch_bounds__(256) void transpose_bf16(const float* __restrict__ src,
                                                      u16* __restrict__ dst,
                                                      int N, int K) {
    __shared__ float tile[32][33];
    const int nb = blockIdx.x * 32, kb = blockIdx.y * 32;
    const int tx = threadIdx.x, ty = threadIdx.y;  // 32 x 8
#pragma unroll
    for (int i = 0; i < 4; ++i) {
        int k = kb + ty + 8 * i, n = nb + tx;
        tile[ty + 8 * i][tx] = (n < N) ? src[(size_t)k * N + n] : 0.f;
    }
    __syncthreads();
#pragma unroll
    for (int i = 0; i < 4; ++i) {
        int n = nb + ty + 8 * i, k = kb + tx;
        dst[(size_t)n * K + k] = f2bf(tile[tx][ty + 8 * i]);
    }
}

// ---------------- RoPE cos/sin table: float2 per (s,i) ----------------------
__global__ __launch_bounds__(256) void rope_table_kernel(float* __restrict__ tab) {
    int gid = blockIdx.x * 256 + threadIdx.x;  // < SEQ*32
    int i = gid & 31, s = gid >> 5;
    float freq = __expf(-(float)(2 * i) / 64.0f * 9.210340371976184f);
    float ang = (float)s * freq;
    tab[2 * gid]     = cosf(ang);
    tab[2 * gid + 1] = sinf(ang);
}

// ---------------- m97-style bf16 GEMM core with fused epilogues -------------
// C = A[M,K] @ BT[N,K]^T.  128x128 tile, 4 waves, BK=32, global_load_lds(16).
// EPI 0 (QKV): cols<2048 -> q_bf bf16*oscale with fused RoPE on pe cols
//              cols>=2048 -> kv fp32 (stride KV_W)
// EPI 1 (F32): plain fp32, stride N
// EPI 2 (KVB): scatter k_nope -> K_all (swizzled) and v -> Vt (transposed+swz)
template <int EPI>
__global__ __launch_bounds__(256) void gemm_core(const u16* __restrict__ A,
                                                 const u16* __restrict__ BT,
                                                 void* __restrict__ out0,
                                                 void* __restrict__ out1,
                                                 const float* __restrict__ tab,
                                                 int M, int N, int K, float oscale) {
    __shared__ u16 As[128 * 32];
    __shared__ u16 Bs[128 * 32];
    const int tid = threadIdx.x;
    const int w = tid >> 6, l = tid & 63;
    const int lr = l & 15, lg = l >> 4;
    const int wr = w >> 1, wc = w & 1;
    const int row0 = blockIdx.y * 128, col0 = blockIdx.x * 128;

    f32x4 acc[4][4];
#pragma unroll
    for (int a = 0; a < 4; ++a)
#pragma unroll
        for (int b = 0; b < 4; ++b) acc[a][b] = (f32x4){0.f, 0.f, 0.f, 0.f};

    const u16* ga = A + (size_t)(row0 + 32 * w + (l >> 2)) * K + 8 * (l & 3);
    const u16* gb = BT + (size_t)(col0 + 32 * w + (l >> 2)) * K + 8 * (l & 3);
    u16* la = As + w * 1024;
    u16* lb = Bs + w * 1024;

    for (int k0 = 0; k0 < K; k0 += 32) {
        __syncthreads();
        gload16(ga + k0, la);
        gload16(ga + (size_t)16 * K + k0, la + 512);
        gload16(gb + k0, lb);
        gload16(gb + (size_t)16 * K + k0, lb + 512);
        __syncthreads();
        bf16x8 af[4], bfr[4];
#pragma unroll
        for (int mi = 0; mi < 4; ++mi)
            af[mi] = *(const bf16x8*)&As[(64 * wr + 16 * mi + lr) * 32 + 8 * lg];
#pragma unroll
        for (int ni = 0; ni < 4; ++ni)
            bfr[ni] = *(const bf16x8*)&Bs[(64 * wc + 16 * ni + lr) * 32 + 8 * lg];
#pragma unroll
        for (int mi = 0; mi < 4; ++mi)
#pragma unroll
            for (int ni = 0; ni < 4; ++ni)
                acc[mi][ni] = __builtin_amdgcn_mfma_f32_16x16x32_bf16(af[mi], bfr[ni], acc[mi][ni], 0, 0, 0);
    }

    if (EPI == 0) {
        if (col0 < 2048) {
            u16* q = (u16*)out0;
            const bool pe = (wc == 1);  // within-head offset 64..127 -> rope half
#pragma unroll
            for (int mi = 0; mi < 4; ++mi)
#pragma unroll
                for (int ni = 0; ni < 4; ++ni) {
                    int c = col0 + 64 * wc + 16 * ni + lr;
#pragma unroll
                    for (int j = 0; j < 4; ++j) {
                        int r = row0 + 64 * wr + 16 * mi + 4 * lg + j;
                        float v = acc[mi][ni][j] * oscale;
                        if (pe) {
                            int s = r & (SEQ - 1);
                            int ip = (16 * ni + lr) >> 1;
                            float2 cs = ((const float2*)tab)[s * 32 + ip];
                            float part = __shfl_xor(v, 1);
                            v = (lr & 1) ? (v * cs.x + part * cs.y)
                                         : (v * cs.x - part * cs.y);
                        }
                        q[(size_t)r * 2048 + c] = f2bf(v);
                    }
                }
        } else {
            float* kvp = (float*)out1;
#pragma unroll
            for (int mi = 0; mi < 4; ++mi)
#pragma unroll
                for (int ni = 0; ni < 4; ++ni) {
                    int c = col0 - 2048 + 64 * wc + 16 * ni + lr;
#pragma unroll
                    for (int j = 0; j < 4; ++j) {
                        int r = row0 + 64 * wr + 16 * mi + 4 * lg + j;
                        kvp[(size_t)r * KV_W + c] = acc[mi][ni][j];
                    }
                }
        }
    } else if (EPI == 1) {
        float* C = (float*)out0;
#pragma unroll
        for (int mi = 0; mi < 4; ++mi)
#pragma unroll
            for (int ni = 0; ni < 4; ++ni)
#pragma unroll
                for (int j = 0; j < 4; ++j) {
                    int r = row0 + 64 * wr + 16 * mi + 4 * lg + j;
                    int c = col0 + 64 * wc + 16 * ni + lr;
                    C[(size_t)r * N + c] = acc[mi][ni][j];
                }
    } else {  // EPI == 2: K_all / Vt scatter
        u16* Kall = (u16*)out0;
        u16* Vt   = (u16*)out1;
        const int b  = row0 >> 11;
        const int sb = (row0 & (SEQ - 1)) + 64 * wr + 4 * lg;  // j=0 row's s (per mi add 16*mi)
#pragma unroll
        for (int mi = 0; mi < 4; ++mi) {
            int s0 = sb + 16 * mi;
#pragma unroll
            for (int ni = 0; ni < 4; ++ni) {
                int c = col0 + 64 * wc + 16 * ni + lr;
                int h = (unsigned)c / 192u;
                int cr = c - h * 192;
                int bh = b * NHEAD + h;
                if (cr < 64) {
#pragma unroll
                    for (int j = 0; j < 4; ++j) {
                        int s = s0 + j;
                        Kall[((size_t)bh * SEQ + s) * 128 + (cr ^ ((s & 7) << 3))] = f2bf(acc[mi][ni][j]);
                    }
                } else {
                    int d = cr - 64;
                    union { u16 u[4]; uint2 v; } pk;
#pragma unroll
                    for (int j = 0; j < 4; ++j) pk.u[j] = f2bf(acc[mi][ni][j]);
                    size_t base = ((size_t)bh * 128 + d) * SEQ + (s0 & ~63);
                    *(uint2*)&Vt[base + ((s0 & 63) ^ ((d & 7) << 3))] = pk.v;
                }
            }
        }
    }
}

// ---------------- RMS norm: kv fp32 [NTOK][640] cols 0..511 -> bf16 ---------
__global__ __launch_bounds__(256) void rmsnorm_bf(const float* __restrict__ kv,
                                                  const float* __restrict__ w,
                                                  u16* __restrict__ c_norm) {
    __shared__ float red[256];
    const int row = blockIdx.x, t = threadIdx.x;
    const float* src = kv + (size_t)row * KV_W;
    float v0 = src[t], v1 = src[t + 256];
    red[t] = v0 * v0 + v1 * v1;
    __syncthreads();
    for (int s = 128; s > 0; s >>= 1) {
        if (t < s) red[t] += red[t + s];
        __syncthreads();
    }
    const float inv = rsqrtf(red[0] / (float)KV_RANK + EPS_F);
    u16* dst = c_norm + (size_t)row * KV_RANK;
    dst[t]       = f2bf(v0 * inv * w[t]);
    dst[t + 256] = f2bf(v1 * inv * w[t + 256]);
}

// ------- build k_pe: kv cols 512..575 -> rope -> all 16 head slices ---------
__global__ __launch_bounds__(256) void build_kpe(const float* __restrict__ kv,
                                                 const float* __restrict__ tab,
                                                 u16* __restrict__ K_all) {
    const int gid = blockIdx.x * 256 + threadIdx.x;  // < NTOK*16
    const int dq = gid & 15;
    const int s = (gid >> 4) & (SEQ - 1);
    const int b = gid >> 15;
    const float* src = kv + (size_t)(b * SEQ + s) * KV_W + KV_RANK + 4 * dq;
    float4 v = *(const float4*)src;
    const int i0 = 2 * dq;
    float2 cs0 = ((const float2*)tab)[s * 32 + i0];
    float2 cs1 = ((const float2*)tab)[s * 32 + i0 + 1];
    union { u16 u[4]; uint2 w; } pk;
    pk.u[0] = f2bf(v.x * cs0.x - v.y * cs0.y);
    pk.u[1] = f2bf(v.y * cs0.x + v.x * cs0.y);
    pk.u[2] = f2bf(v.z * cs1.x - v.w * cs1.y);
    pk.u[3] = f2bf(v.w * cs1.x + v.z * cs1.y);
    const int idx = (64 + 4 * dq) ^ ((s & 7) << 3);
#pragma unroll
    for (int h = 0; h < NHEAD; ++h) {
        int bh = b * NHEAD + h;
        *(uint2*)&K_all[((size_t)bh * SEQ + s) * 128 + idx] = pk.w;
    }
}

// ---------------- flash attention: staged LDS double-buffer -----------------
// 512 thr (8 waves), QTILE=128 (16 q-rows/wave), KTILE=64.
// S^T = mfma(K,Q), O^T = mfma(V^T,P^T): q lane-local, stats in-lane.
// Softmax in log2 domain (scale*log2e folded into q); defer-max T13.
#define QTILE 128
#define KTILE 64

__global__ __launch_bounds__(512, 4) void attn_mfma(const u16* __restrict__ q_bf,
                                                    const u16* __restrict__ K_all,
                                                    const u16* __restrict__ Vt,
                                                    u16* __restrict__ attn_bf) {
    __shared__ u16 Kbuf[2][KTILE * 128];   // 2 x 16KB
    __shared__ u16 Vbuf[2][128 * KTILE];   // 2 x 16KB
    __shared__ u16 Plds[8][16 * KTILE];    // 16KB, wave-private

    const int idx = blockIdx.x;                       // 0..511
    const int bh = (idx & 7) + 8 * (idx >> 7);
    const int qb = (idx >> 3) & 15;
    const int qbase = (15 - qb) * QTILE;              // long blocks first
    const int b = bh >> 4, h = bh & 15;

    const int tid = threadIdx.x;
    const int w = tid >> 6, l = tid & 63;
    const int lr = l & 15, lg = l >> 4;
    const u16* Kb = K_all + (size_t)bh * SEQ * 128;
    const u16* Vb = Vt + (size_t)bh * 128 * SEQ;
    const int qg = qbase + 16 * w + lr;
    const int sw = (lr & 7) << 3;                     // u16-index XOR

    const u16* qrow = q_bf + (size_t)(b * SEQ + qg) * 2048 + h * QK_HEAD;
    bf16x8 qf[4];
#pragma unroll
    for (int dc = 0; dc < 4; ++dc) qf[dc] = *(const bf16x8*)(qrow + dc * 32 + lg * 8);

    f32x4 oacc[8];
#pragma unroll
    for (int ft = 0; ft < 8; ++ft) oacc[ft] = (f32x4){0.f, 0.f, 0.f, 0.f};
    float m_r = -1e30f, l_r = 0.f;

    u16* pw = Plds[w];
    const int nkt = qbase / KTILE + 2;

    auto stage = [&](int bufi, int kt) {
        const int k0 = kt * KTILE;
        u16* kb = Kbuf[bufi];
        u16* vb = Vbuf[bufi];
#pragma unroll
        for (int it = 0; it < 2; ++it) {
            int ci = it * 512 + tid;
            gload16(Kb + (((size_t)(k0 + (ci >> 4))) << 7) + ((ci & 15) << 3),
                    kb + ((it * 512 + (w << 6)) << 3));
        }
#pragma unroll
        for (int it = 0; it < 2; ++it) {
            int ci = it * 512 + tid;
            gload16(Vb + (size_t)(ci >> 3) * SEQ + k0 + ((ci & 7) << 3),
                    vb + ((it * 512 + (w << 6)) << 3));
        }
    };

    stage(0, 0);
    int cur = 0;
    for (int kt = 0; kt < nkt; ++kt) {
        const int k0 = kt * KTILE;
        if (kt + 1 < nkt) {
            stage(cur ^ 1, kt + 1);
            asm volatile("s_waitcnt vmcnt(4)" ::: "memory");
        } else {
            asm volatile("s_waitcnt vmcnt(0)" ::: "memory");
        }
        __builtin_amdgcn_s_barrier();
        __builtin_amdgcn_sched_barrier(0);

        if (k0 <= qbase + 16 * w + 15) {              // wave-uniform skip
            const u16* kb = Kbuf[cur];
            const u16* vb = Vbuf[cur];

            // ---- S^T = K @ Q^T ----
            f32x4 s[4];
            __builtin_amdgcn_s_setprio(1);
#pragma unroll
            for (int f = 0; f < 4; ++f) {
                s[f] = (f32x4){0.f, 0.f, 0.f, 0.f};
#pragma unroll
                for (int dc = 0; dc < 4; ++dc) {
                    bf16x8 kf = *(const bf16x8*)&kb[(16 * f + lr) * 128 + ((32 * dc + 8 * lg) ^ sw)];
                    s[f] = __builtin_amdgcn_mfma_f32_16x16x32_bf16(kf, qf[dc], s[f], 0, 0, 0);
                }
            }
            __builtin_amdgcn_s_setprio(0);

            // ---- causal mask (diagonal region only) ----
            if (k0 + KTILE - 1 > qbase + 16 * w) {
#pragma unroll
                for (int f = 0; f < 4; ++f)
#pragma unroll
                    for (int j = 0; j < 4; ++j)
                        if (k0 + 16 * f + 4 * lg + j > qg) s[f][j] = -1e30f;
            }

            // ---- online softmax (log2 domain), defer-max ----
            float t0 = fmaxf(fmaxf(s[0][0], s[0][1]), fmaxf(s[0][2], s[0][3]));
            float t1 = fmaxf(fmaxf(s[1][0], s[1][1]), fmaxf(s[1][2], s[1][3]));
            float t2 = fmaxf(fmaxf(s[2][0], s[2][1]), fmaxf(s[2][2], s[2][3]));
            float t3 = fmaxf(fmaxf(s[3][0], s[3][1]), fmaxf(s[3][2], s[3][3]));
            float t = fmaxf(fmaxf(t0, t1), fmaxf(t2, t3));
            t = fmaxf(t, __shfl_xor(t, 16));
            t = fmaxf(t, __shfl_xor(t, 32));
            bool up = (t > m_r + 11.5f);              // 2^11.5 headroom
            float newm = up ? t : m_r;
            float sf_ = up ? exp2f(m_r - t) : 1.0f;
            m_r = newm;
            float rs = 0.f;
#pragma unroll
            for (int f = 0; f < 4; ++f)
#pragma unroll
                for (int j = 0; j < 4; ++j) {
                    float p = exp2f(s[f][j] - newm);
                    s[f][j] = p;
                    rs += p;
                }
            rs += __shfl_xor(rs, 16);
            rs += __shfl_xor(rs, 32);
            l_r = l_r * sf_ + rs;
            if (__any(up)) {
#pragma unroll
                for (int ft = 0; ft < 8; ++ft)
#pragma unroll
                    for (int j = 0; j < 4; ++j) oacc[ft][j] *= sf_;
            }

            // ---- P -> wave-private LDS, re-layout to B-fragment ----
#pragma unroll
            for (int f = 0; f < 4; ++f) {
                union { u16 u[4]; uint2 v; } pk;
#pragma unroll
                for (int j = 0; j < 4; ++j) pk.u[j] = f2bf(s[f][j]);
                *(uint2*)&pw[lr * 64 + ((16 * f + 4 * lg) ^ sw)] = pk.v;
            }
            asm volatile("s_waitcnt lgkmcnt(0)" ::: "memory");
            bf16x8 pfr[2];
#pragma unroll
            for (int ks = 0; ks < 2; ++ks)
                pfr[ks] = *(const bf16x8*)&pw[lr * 64 + ((32 * ks + 8 * lg) ^ sw)];

            // ---- O^T += V^T @ P^T ----
            __builtin_amdgcn_s_setprio(1);
#pragma unroll
            for (int ft = 0; ft < 8; ++ft) {
                int d = 16 * ft + lr;
#pragma unroll
                for (int ks = 0; ks < 2; ++ks) {
                    bf16x8 vf = *(const bf16x8*)&vb[d * 64 + ((32 * ks + 8 * lg) ^ sw)];
                    oacc[ft] = __builtin_amdgcn_mfma_f32_16x16x32_bf16(vf, pfr[ks], oacc[ft], 0, 0, 0);
                }
            }
            __builtin_amdgcn_s_setprio(0);
        }
        __builtin_amdgcn_s_barrier();
        cur ^= 1;
    }

    const float inv = 1.0f / l_r;
    u16* orow = attn_bf + (size_t)(b * SEQ + qg) * 2048 + h * V_HEAD;
#pragma unroll
    for (int ft = 0; ft < 8; ++ft) {
        union { u16 u[4]; uint2 v; } ok;
#pragma unroll
        for (int j = 0; j < 4; ++j) ok.u[j] = f2bf(oacc[ft][j] * inv);
        *(uint2*)(orow + 16 * ft + 4 * lg) = ok.v;
    }
}

// ------------------------------------------------------------------
extern "C" void kernel_launch(void* const* d_in, const int* in_sizes, int n_in,
                              void* d_out, int out_size, void* d_ws, size_t ws_size,
                              hipStream_t stream) {
    const float* x         = (const float*)d_in[0];
    const float* w_query   = (const float*)d_in[1];
    const float* wkv_a     = (const float*)d_in[2];
    const float* wkv_b     = (const float*)d_in[3];
    const float* kv_norm_w = (const float*)d_in[4];
    const float* out_proj  = (const float*)d_in[5];

    u16* x_bf     = (u16*)d_ws;                       // 8M u16 (aliased by attn_bf)
    u16* q_bf     = x_bf + (size_t)8388608;           // 8M
    u16* c_norm   = q_bf + (size_t)8388608;           // 2M
    u16* kvdec_bf = c_norm + (size_t)2097152;         // (unused now)
    u16* K_all    = kvdec_bf + (size_t)12582912;      // 8.39M
    u16* Vt       = K_all + (size_t)8388608;          // 8.39M
    u16* wT       = Vt + (size_t)8388608;             // wqT(4M) + wkvaT(1.31M) contiguous
    u16* wkvaT    = wT + (size_t)4194304;
    u16* wkvbT    = wkvaT + (size_t)1310720;          // 1.57M
    u16* opT      = wkvbT + (size_t)1572864;          // 4M
    float* kv     = (float*)(opT + (size_t)4194304);  // 2.62M floats
    float* tab    = kv + (size_t)2621440;             // 131072 floats
    u16* attn_bf  = x_bf;                             // alias (x_bf dead after merged GEMM)
    float* out = (float*)d_out;

    dim3 tb(32, 8);
    // 128^-0.5 * log2(e): QK scale + exp->exp2 conversion folded into q
    const float qscale2 = 0.08838834764831845f * 1.4426950408889634f;

    convert_bf16<<<8192, 256, 0, stream>>>(x, x_bf, 2097152);
    transpose_bf16<<<dim3(64, 64), tb, 0, stream>>>(w_query, wT, 2048, 2048);
    transpose_bf16<<<dim3(20, 64), tb, 0, stream>>>(wkv_a, wkvaT, 576, 2048);  // pad->640
    transpose_bf16<<<dim3(96, 16), tb, 0, stream>>>(wkv_b, wkvbT, 3072, 512);
    transpose_bf16<<<dim3(64, 64), tb, 0, stream>>>(out_proj, opT, 2048, 2048);
    rope_table_kernel<<<256, 256, 0, stream>>>(tab);

    // merged q + kv GEMM: N = 2048 + 640 = 2688, fused RoPE(q) epilogue
    gemm_core<0><<<dim3(21, 32), 256, 0, stream>>>(x_bf, wT, q_bf, kv, tab,
                                                   NTOK, 2688, 2048, qscale2);
    rmsnorm_bf<<<NTOK, 256, 0, stream>>>(kv, kv_norm_w, c_norm);
    // wkv_b GEMM with fused K_all/Vt scatter epilogue
    gemm_core<2><<<dim3(24, 32), 256, 0, stream>>>(c_norm, wkvbT, K_all, Vt, nullptr,
                                                   NTOK, 3072, 512, 1.0f);
    build_kpe<<<256, 256, 0, stream>>>(kv, tab, K_all);

    attn_mfma<<<512, 512, 0, stream>>>(q_bf, K_all, Vt, attn_bf);

    gemm_core<1><<<dim3(16, 32), 256, 0, stream>>>(attn_bf, opT, out, nullptr, nullptr,
                                                   NTOK, 2048, 2048, 1.0f);
}

// Round 7
// 266.816 us; speedup vs baseline: 2.6682x; 1.1448x over previous
//
#include <hip/hip_runtime.h>
#include <hip/hip_bf16.h>
#include <math.h>

#define BATCH   2
#define SEQ     2048
#define D_IN    2048
#define NHEAD   16
#define QK_ROPE 64
#define QK_NOPE 64
#define QK_HEAD 128
#define V_HEAD  128
#define KV_RANK 512
#define KV_W    640          // kv row stride (576 padded to 640)
#define NTOK    (BATCH*SEQ)  // 4096
#define EPS_F   1e-6f

typedef unsigned short u16;
typedef short bf16x8 __attribute__((ext_vector_type(8)));
typedef float f32x4  __attribute__((ext_vector_type(4)));

__device__ __forceinline__ u16 f2bf(float f) {
    unsigned u = __float_as_uint(f);
    return (u16)((u + 0x7fffu + ((u >> 16) & 1u)) >> 16);
}
__device__ __forceinline__ float bf2f(u16 u) {
    return __uint_as_float(((unsigned)u) << 16);
}
__device__ __forceinline__ float exp2_hw(float x) {
    float r;
    asm volatile("v_exp_f32 %0, %1\n\ts_nop 0" : "=v"(r) : "v"(x));
    return r;
}
__device__ __forceinline__ void gload16(const void* g, void* l) {
    __builtin_amdgcn_global_load_lds((const __attribute__((address_space(1))) unsigned int*)g,
                                     (__attribute__((address_space(3))) unsigned int*)l, 16, 0, 0);
}

// ---------------- fp32 -> bf16 flat convert (4 elems/thread) ----------------
__global__ __launch_bounds__(256) void convert_bf16(const float* __restrict__ src,
                                                    u16* __restrict__ dst, int n4) {
    int gid = blockIdx.x * 256 + threadIdx.x;
    if (gid >= n4) return;
    float4 v = ((const float4*)src)[gid];
    unsigned lo = (unsigned)f2bf(v.x) | ((unsigned)f2bf(v.y) << 16);
    unsigned hi = (unsigned)f2bf(v.z) | ((unsigned)f2bf(v.w) << 16);
    ((uint2*)dst)[gid] = make_uint2(lo, hi);
}

// -------- transpose+convert: src fp32 [K][N] -> dst bf16 [Npad][K] ----------
__global__ __launch_bounds__(256) void transpose_bf16(const float* __restrict__ src,
                                                      u16* __restrict__ dst,
                                                      int N, int K) {
    __shared__ float tile[32][33];
    const int nb = blockIdx.x * 32, kb = blockIdx.y * 32;
    const int tx = threadIdx.x, ty = threadIdx.y;  // 32 x 8
#pragma unroll
    for (int i = 0; i < 4; ++i) {
        int k = kb + ty + 8 * i, n = nb + tx;
        tile[ty + 8 * i][tx] = (n < N) ? src[(size_t)k * N + n] : 0.f;
    }
    __syncthreads();
#pragma unroll
    for (int i = 0; i < 4; ++i) {
        int n = nb + ty + 8 * i, k = kb + tx;
        dst[(size_t)n * K + k] = f2bf(tile[tx][ty + 8 * i]);
    }
}

// ---------------- RoPE cos/sin table: float2 per (s,i) ----------------------
__global__ __launch_bounds__(256) void rope_table_kernel(float* __restrict__ tab) {
    int gid = blockIdx.x * 256 + threadIdx.x;  // < SEQ*32
    int i = gid & 31, s = gid >> 5;
    float freq = __expf(-(float)(2 * i) / 64.0f * 9.210340371976184f);
    float ang = (float)s * freq;
    tab[2 * gid]     = cosf(ang);
    tab[2 * gid + 1] = sinf(ang);
}

// ---------------- m97-style bf16 GEMM core with fused epilogues -------------
// C = A[M,K] @ BT[N,K]^T.  128x128 tile, 4 waves, BK=32, global_load_lds(16).
// EPI 0 (QKV): cols<2048 -> q_bf bf16*oscale with fused RoPE on pe cols
//              cols>=2048 -> kv fp32 (stride KV_W)
// EPI 1 (F32): plain fp32, stride N
// EPI 2 (KVB): scatter k_nope -> K_all (swizzled) and v -> Vt (transposed+swz)
template <int EPI>
__global__ __launch_bounds__(256) void gemm_core(const u16* __restrict__ A,
                                                 const u16* __restrict__ BT,
                                                 void* __restrict__ out0,
                                                 void* __restrict__ out1,
                                                 const float* __restrict__ tab,
                                                 int M, int N, int K, float oscale) {
    __shared__ u16 As[128 * 32];
    __shared__ u16 Bs[128 * 32];
    const int tid = threadIdx.x;
    const int w = tid >> 6, l = tid & 63;
    const int lr = l & 15, lg = l >> 4;
    const int wr = w >> 1, wc = w & 1;
    const int row0 = blockIdx.y * 128, col0 = blockIdx.x * 128;

    f32x4 acc[4][4];
#pragma unroll
    for (int a = 0; a < 4; ++a)
#pragma unroll
        for (int b = 0; b < 4; ++b) acc[a][b] = (f32x4){0.f, 0.f, 0.f, 0.f};

    const u16* ga = A + (size_t)(row0 + 32 * w + (l >> 2)) * K + 8 * (l & 3);
    const u16* gb = BT + (size_t)(col0 + 32 * w + (l >> 2)) * K + 8 * (l & 3);
    u16* la = As + w * 1024;
    u16* lb = Bs + w * 1024;

    for (int k0 = 0; k0 < K; k0 += 32) {
        __syncthreads();
        gload16(ga + k0, la);
        gload16(ga + (size_t)16 * K + k0, la + 512);
        gload16(gb + k0, lb);
        gload16(gb + (size_t)16 * K + k0, lb + 512);
        __syncthreads();
        bf16x8 af[4], bfr[4];
#pragma unroll
        for (int mi = 0; mi < 4; ++mi)
            af[mi] = *(const bf16x8*)&As[(64 * wr + 16 * mi + lr) * 32 + 8 * lg];
#pragma unroll
        for (int ni = 0; ni < 4; ++ni)
            bfr[ni] = *(const bf16x8*)&Bs[(64 * wc + 16 * ni + lr) * 32 + 8 * lg];
#pragma unroll
        for (int mi = 0; mi < 4; ++mi)
#pragma unroll
            for (int ni = 0; ni < 4; ++ni)
                acc[mi][ni] = __builtin_amdgcn_mfma_f32_16x16x32_bf16(af[mi], bfr[ni], acc[mi][ni], 0, 0, 0);
    }

    if (EPI == 0) {
        if (col0 < 2048) {
            u16* q = (u16*)out0;
            const bool pe = (wc == 1);  // within-head offset 64..127 -> rope half
#pragma unroll
            for (int mi = 0; mi < 4; ++mi)
#pragma unroll
                for (int ni = 0; ni < 4; ++ni) {
                    int c = col0 + 64 * wc + 16 * ni + lr;
#pragma unroll
                    for (int j = 0; j < 4; ++j) {
                        int r = row0 + 64 * wr + 16 * mi + 4 * lg + j;
                        float v = acc[mi][ni][j] * oscale;
                        if (pe) {
                            int s = r & (SEQ - 1);
                            int ip = (16 * ni + lr) >> 1;
                            float2 cs = ((const float2*)tab)[s * 32 + ip];
                            float part = __shfl_xor(v, 1);
                            v = (lr & 1) ? (v * cs.x + part * cs.y)
                                         : (v * cs.x - part * cs.y);
                        }
                        q[(size_t)r * 2048 + c] = f2bf(v);
                    }
                }
        } else {
            float* kvp = (float*)out1;
#pragma unroll
            for (int mi = 0; mi < 4; ++mi)
#pragma unroll
                for (int ni = 0; ni < 4; ++ni) {
                    int c = col0 - 2048 + 64 * wc + 16 * ni + lr;
#pragma unroll
                    for (int j = 0; j < 4; ++j) {
                        int r = row0 + 64 * wr + 16 * mi + 4 * lg + j;
                        kvp[(size_t)r * KV_W + c] = acc[mi][ni][j];
                    }
                }
        }
    } else if (EPI == 1) {
        float* C = (float*)out0;
#pragma unroll
        for (int mi = 0; mi < 4; ++mi)
#pragma unroll
            for (int ni = 0; ni < 4; ++ni)
#pragma unroll
                for (int j = 0; j < 4; ++j) {
                    int r = row0 + 64 * wr + 16 * mi + 4 * lg + j;
                    int c = col0 + 64 * wc + 16 * ni + lr;
                    C[(size_t)r * N + c] = acc[mi][ni][j];
                }
    } else {  // EPI == 2: K_all / Vt scatter
        u16* Kall = (u16*)out0;
        u16* Vt   = (u16*)out1;
        const int b  = row0 >> 11;
        const int sb = (row0 & (SEQ - 1)) + 64 * wr + 4 * lg;  // j=0 row's s (per mi add 16*mi)
#pragma unroll
        for (int mi = 0; mi < 4; ++mi) {
            int s0 = sb + 16 * mi;
#pragma unroll
            for (int ni = 0; ni < 4; ++ni) {
                int c = col0 + 64 * wc + 16 * ni + lr;
                int h = (unsigned)c / 192u;
                int cr = c - h * 192;
                int bh = b * NHEAD + h;
                if (cr < 64) {
#pragma unroll
                    for (int j = 0; j < 4; ++j) {
                        int s = s0 + j;
                        Kall[((size_t)bh * SEQ + s) * 128 + (cr ^ ((s & 7) << 3))] = f2bf(acc[mi][ni][j]);
                    }
                } else {
                    int d = cr - 64;
                    union { u16 u[4]; uint2 v; } pk;
#pragma unroll
                    for (int j = 0; j < 4; ++j) pk.u[j] = f2bf(acc[mi][ni][j]);
                    size_t base = ((size_t)bh * 128 + d) * SEQ + (s0 & ~63);
                    *(uint2*)&Vt[base + ((s0 & 63) ^ ((d & 7) << 3))] = pk.v;
                }
            }
        }
    }
}

// ---------------- RMS norm: kv fp32 [NTOK][640] cols 0..511 -> bf16 ---------
__global__ __launch_bounds__(256) void rmsnorm_bf(const float* __restrict__ kv,
                                                  const float* __restrict__ w,
                                                  u16* __restrict__ c_norm) {
    __shared__ float red[256];
    const int row = blockIdx.x, t = threadIdx.x;
    const float* src = kv + (size_t)row * KV_W;
    float v0 = src[t], v1 = src[t + 256];
    red[t] = v0 * v0 + v1 * v1;
    __syncthreads();
    for (int s = 128; s > 0; s >>= 1) {
        if (t < s) red[t] += red[t + s];
        __syncthreads();
    }
    const float inv = rsqrtf(red[0] / (float)KV_RANK + EPS_F);
    u16* dst = c_norm + (size_t)row * KV_RANK;
    dst[t]       = f2bf(v0 * inv * w[t]);
    dst[t + 256] = f2bf(v1 * inv * w[t + 256]);
}

// ------- build k_pe: kv cols 512..575 -> rope -> all 16 head slices ---------
__global__ __launch_bounds__(256) void build_kpe(const float* __restrict__ kv,
                                                 const float* __restrict__ tab,
                                                 u16* __restrict__ K_all) {
    const int gid = blockIdx.x * 256 + threadIdx.x;  // < NTOK*16
    const int dq = gid & 15;
    const int s = (gid >> 4) & (SEQ - 1);
    const int b = gid >> 15;
    const float* src = kv + (size_t)(b * SEQ + s) * KV_W + KV_RANK + 4 * dq;
    float4 v = *(const float4*)src;
    const int i0 = 2 * dq;
    float2 cs0 = ((const float2*)tab)[s * 32 + i0];
    float2 cs1 = ((const float2*)tab)[s * 32 + i0 + 1];
    union { u16 u[4]; uint2 w; } pk;
    pk.u[0] = f2bf(v.x * cs0.x - v.y * cs0.y);
    pk.u[1] = f2bf(v.y * cs0.x + v.x * cs0.y);
    pk.u[2] = f2bf(v.z * cs1.x - v.w * cs1.y);
    pk.u[3] = f2bf(v.w * cs1.x + v.z * cs1.y);
    const int idx = (64 + 4 * dq) ^ ((s & 7) << 3);
#pragma unroll
    for (int h = 0; h < NHEAD; ++h) {
        int bh = b * NHEAD + h;
        *(uint2*)&K_all[((size_t)bh * SEQ + s) * 128 + idx] = pk.w;
    }
}

// ---------------- flash attention: pair-balanced blocks ---------------------
// 256 thr (4 waves), QTILE=64 (16 q-rows/wave), KTILE=64.
// Each block processes Q-tiles (31-pi) then (pi): nkt total = 33 for all.
// S^T = mfma(K,Q), O^T = mfma(V^T,P^T): q lane-local, stats in-lane.
// K/V double-buffered via global_load_lds; counted vmcnt(8); asm v_exp_f32.
#define QTILE 64
#define KTILE 64

__global__ __launch_bounds__(256, 2) void attn_mfma(const u16* __restrict__ q_bf,
                                                    const u16* __restrict__ K_all,
                                                    const u16* __restrict__ Vt,
                                                    u16* __restrict__ attn_bf) {
    __shared__ u16 Kbuf[2][KTILE * 128];   // 2 x 16KB
    __shared__ u16 Vbuf[2][128 * KTILE];   // 2 x 16KB
    __shared__ u16 Plds[4][16 * KTILE];    // 8KB, wave-private

    const int idx = blockIdx.x;                       // 0..511
    const int bh = (idx & 7) + 8 * (idx >> 7);        // 4 heads per XCD (4MB = L2)
    const int pi = (idx >> 3) & 15;                   // pair index
    const int b = bh >> 4, h = bh & 15;

    const int tid = threadIdx.x;
    const int w = tid >> 6, l = tid & 63;
    const int lr = l & 15, lg = l >> 4;
    const u16* Kb = K_all + (size_t)bh * SEQ * 128;
    const u16* Vb = Vt + (size_t)bh * 128 * SEQ;
    const int sw = (lr & 7) << 3;                     // u16-index XOR
    u16* pw = Plds[w];

    auto stage = [&](int bufi, int k0) {
        u16* kb = Kbuf[bufi];
        u16* vb = Vbuf[bufi];
#pragma unroll
        for (int it = 0; it < 4; ++it) {              // K: 1024 x 16B chunks
            int ci = it * 256 + tid;
            gload16(Kb + (((size_t)(k0 + (ci >> 4))) << 7) + ((ci & 15) << 3),
                    kb + (ci << 3));
        }
#pragma unroll
        for (int it = 0; it < 4; ++it) {              // V: 1024 x 16B chunks
            int ci = it * 256 + tid;
            gload16(Vb + (size_t)(ci >> 3) * SEQ + k0 + ((ci & 7) << 3),
                    vb + (ci << 3));
        }
    };

    const int qbA = (31 - pi) * QTILE;
    const int qbB = pi * QTILE;

    stage(0, 0);
    int cur = 0;
    for (int half = 0; half < 2; ++half) {
        const int qbase = half ? qbB : qbA;
        const int nkt = (qbase >> 6) + 1;
        const int qg = qbase + 16 * w + lr;

        const u16* qrow = q_bf + (size_t)(b * SEQ + qg) * 2048 + h * QK_HEAD;
        bf16x8 qf[4];
#pragma unroll
        for (int dc = 0; dc < 4; ++dc) qf[dc] = *(const bf16x8*)(qrow + dc * 32 + lg * 8);

        f32x4 oacc[8];
#pragma unroll
        for (int ft = 0; ft < 8; ++ft) oacc[ft] = (f32x4){0.f, 0.f, 0.f, 0.f};
        float m_r = -1e30f, l_r = 0.f;

        for (int kt = 0; kt < nkt; ++kt) {
            const int k0 = kt * KTILE;
            if (kt + 1 < nkt) {
                stage(cur ^ 1, k0 + KTILE);
                asm volatile("s_waitcnt vmcnt(8)" ::: "memory");
            } else if (half == 0) {
                stage(cur ^ 1, 0);                    // prefetch half-B tile 0
                asm volatile("s_waitcnt vmcnt(8)" ::: "memory");
            } else {
                asm volatile("s_waitcnt vmcnt(0)" ::: "memory");
            }
            __builtin_amdgcn_s_barrier();
            __builtin_amdgcn_sched_barrier(0);

            const u16* kb = Kbuf[cur];
            const u16* vb = Vbuf[cur];

            // ---- S^T = K @ Q^T ----
            f32x4 s[4];
            __builtin_amdgcn_s_setprio(1);
#pragma unroll
            for (int f = 0; f < 4; ++f) {
                s[f] = (f32x4){0.f, 0.f, 0.f, 0.f};
#pragma unroll
                for (int dc = 0; dc < 4; ++dc) {
                    bf16x8 kf = *(const bf16x8*)&kb[(16 * f + lr) * 128 + ((32 * dc + 8 * lg) ^ sw)];
                    s[f] = __builtin_amdgcn_mfma_f32_16x16x32_bf16(kf, qf[dc], s[f], 0, 0, 0);
                }
            }
            __builtin_amdgcn_s_setprio(0);

            // ---- causal mask (diagonal tile only) ----
            if (kt == nkt - 1) {
#pragma unroll
                for (int f = 0; f < 4; ++f)
#pragma unroll
                    for (int j = 0; j < 4; ++j)
                        if (k0 + 16 * f + 4 * lg + j > qg) s[f][j] = -1e30f;
            }

            // ---- online softmax (log2 domain), defer-max, asm exp2 ----
            float t0 = fmaxf(fmaxf(s[0][0], s[0][1]), fmaxf(s[0][2], s[0][3]));
            float t1 = fmaxf(fmaxf(s[1][0], s[1][1]), fmaxf(s[1][2], s[1][3]));
            float t2 = fmaxf(fmaxf(s[2][0], s[2][1]), fmaxf(s[2][2], s[2][3]));
            float t3 = fmaxf(fmaxf(s[3][0], s[3][1]), fmaxf(s[3][2], s[3][3]));
            float t = fmaxf(fmaxf(t0, t1), fmaxf(t2, t3));
            t = fmaxf(t, __shfl_xor(t, 16));
            t = fmaxf(t, __shfl_xor(t, 32));
            bool up = (t > m_r + 11.5f);              // 2^11.5 headroom
            float newm = up ? t : m_r;
            float sf_ = up ? exp2_hw(m_r - t) : 1.0f;
            m_r = newm;
            float rs = 0.f;
#pragma unroll
            for (int f = 0; f < 4; ++f)
#pragma unroll
                for (int j = 0; j < 4; ++j) {
                    float p = exp2_hw(s[f][j] - newm);
                    s[f][j] = p;
                    rs += p;
                }
            rs += __shfl_xor(rs, 16);
            rs += __shfl_xor(rs, 32);
            l_r = l_r * sf_ + rs;
            if (__any(up)) {
#pragma unroll
                for (int ft = 0; ft < 8; ++ft)
#pragma unroll
                    for (int j = 0; j < 4; ++j) oacc[ft][j] *= sf_;
            }

            // ---- P -> wave-private LDS, re-layout to B-fragment ----
#pragma unroll
            for (int f = 0; f < 4; ++f) {
                union { u16 u[4]; uint2 v; } pk;
#pragma unroll
                for (int j = 0; j < 4; ++j) pk.u[j] = f2bf(s[f][j]);
                *(uint2*)&pw[lr * 64 + ((16 * f + 4 * lg) ^ sw)] = pk.v;
            }
            asm volatile("s_waitcnt lgkmcnt(0)" ::: "memory");
            bf16x8 pfr[2];
#pragma unroll
            for (int ks = 0; ks < 2; ++ks)
                pfr[ks] = *(const bf16x8*)&pw[lr * 64 + ((32 * ks + 8 * lg) ^ sw)];

            // ---- O^T += V^T @ P^T ----
            __builtin_amdgcn_s_setprio(1);
#pragma unroll
            for (int ft = 0; ft < 8; ++ft) {
                int d = 16 * ft + lr;
#pragma unroll
                for (int ks = 0; ks < 2; ++ks) {
                    bf16x8 vf = *(const bf16x8*)&vb[d * 64 + ((32 * ks + 8 * lg) ^ sw)];
                    oacc[ft] = __builtin_amdgcn_mfma_f32_16x16x32_bf16(vf, pfr[ks], oacc[ft], 0, 0, 0);
                }
            }
            __builtin_amdgcn_s_setprio(0);

            __builtin_amdgcn_s_barrier();
            cur ^= 1;
        }

        // ---- epilogue for this half ----
        const float inv = 1.0f / l_r;
        u16* orow = attn_bf + (size_t)(b * SEQ + qg) * 2048 + h * V_HEAD;
#pragma unroll
        for (int ft = 0; ft < 8; ++ft) {
            union { u16 u[4]; uint2 v; } ok;
#pragma unroll
            for (int j = 0; j < 4; ++j) ok.u[j] = f2bf(oacc[ft][j] * inv);
            *(uint2*)(orow + 16 * ft + 4 * lg) = ok.v;
        }
    }
}

// ------------------------------------------------------------------
extern "C" void kernel_launch(void* const* d_in, const int* in_sizes, int n_in,
                              void* d_out, int out_size, void* d_ws, size_t ws_size,
                              hipStream_t stream) {
    const float* x         = (const float*)d_in[0];
    const float* w_query   = (const float*)d_in[1];
    const float* wkv_a     = (const float*)d_in[2];
    const float* wkv_b     = (const float*)d_in[3];
    const float* kv_norm_w = (const float*)d_in[4];
    const float* out_proj  = (const float*)d_in[5];

    u16* x_bf     = (u16*)d_ws;                       // 8M u16 (aliased by attn_bf)
    u16* q_bf     = x_bf + (size_t)8388608;           // 8M
    u16* c_norm   = q_bf + (size_t)8388608;           // 2M
    u16* kvdec_bf = c_norm + (size_t)2097152;         // (unused)
    u16* K_all    = kvdec_bf + (size_t)12582912;      // 8.39M
    u16* Vt       = K_all + (size_t)8388608;          // 8.39M
    u16* wT       = Vt + (size_t)8388608;             // wqT(4M) + wkvaT(1.31M) contiguous
    u16* wkvaT    = wT + (size_t)4194304;
    u16* wkvbT    = wkvaT + (size_t)1310720;          // 1.57M
    u16* opT      = wkvbT + (size_t)1572864;          // 4M
    float* kv     = (float*)(opT + (size_t)4194304);  // 2.62M floats
    float* tab    = kv + (size_t)2621440;             // 131072 floats
    u16* attn_bf  = x_bf;                             // alias (x_bf dead after merged GEMM)
    float* out = (float*)d_out;

    dim3 tb(32, 8);
    // 128^-0.5 * log2(e): QK scale + exp->exp2 conversion folded into q
    const float qscale2 = 0.08838834764831845f * 1.4426950408889634f;

    convert_bf16<<<8192, 256, 0, stream>>>(x, x_bf, 2097152);
    transpose_bf16<<<dim3(64, 64), tb, 0, stream>>>(w_query, wT, 2048, 2048);
    transpose_bf16<<<dim3(20, 64), tb, 0, stream>>>(wkv_a, wkvaT, 576, 2048);  // pad->640
    transpose_bf16<<<dim3(96, 16), tb, 0, stream>>>(wkv_b, wkvbT, 3072, 512);
    transpose_bf16<<<dim3(64, 64), tb, 0, stream>>>(out_proj, opT, 2048, 2048);
    rope_table_kernel<<<256, 256, 0, stream>>>(tab);

    // merged q + kv GEMM: N = 2048 + 640 = 2688, fused RoPE(q) epilogue
    gemm_core<0><<<dim3(21, 32), 256, 0, stream>>>(x_bf, wT, q_bf, kv, tab,
                                                   NTOK, 2688, 2048, qscale2);
    rmsnorm_bf<<<NTOK, 256, 0, stream>>>(kv, kv_norm_w, c_norm);
    // wkv_b GEMM with fused K_all/Vt scatter epilogue
    gemm_core<2><<<dim3(24, 32), 256, 0, stream>>>(c_norm, wkvbT, K_all, Vt, nullptr,
                                                   NTOK, 3072, 512, 1.0f);
    build_kpe<<<256, 256, 0, stream>>>(kv, tab, K_all);

    attn_mfma<<<512, 256, 0, stream>>>(q_bf, K_all, Vt, attn_bf);

    gemm_core<1><<<dim3(16, 32), 256, 0, stream>>>(attn_bf, opT, out, nullptr, nullptr,
                                                   NTOK, 2048, 2048, 1.0f);
}